// Round 1
// baseline (433.455 us; speedup 1.0000x reference)
//
#include <hip/hip_runtime.h>
#include <math.h>

#define BB 32
#define SS 48
#define LL 64
#define FF 256
#define KT 16

__global__ __launch_bounds__(256) void ida_kernel(
    const float* __restrict__ features,
    const float* __restrict__ src_locs,
    const float* __restrict__ tar_locs,
    const float* __restrict__ W1,
    const float* __restrict__ b1,
    const float* __restrict__ W2,
    const float* __restrict__ b2,
    float* __restrict__ out)
{
    __shared__ float Xs[LL * FF];        // 64 KiB: feature tile [l][f]
    __shared__ float smem2[KT * FF];     // 16 KiB: W1 K-tile, later SP + wbuf

    const int t = threadIdx.x;
    const int bs = blockIdx.x;
    const int b = bs / SS;

    const float* Xg = features + (size_t)bs * (LL * FF);

    // ---- stage feature tile (flat 16384 floats, float4-coalesced) ----
    {
        const float4* src = (const float4*)Xg;
        float4* dst = (float4*)Xs;
        #pragma unroll
        for (int q = 0; q < 16; ++q)
            dst[t + 256 * q] = src[t + 256 * q];
    }

    const int i = t >> 5;   // row group: rows 8i..8i+7
    const int j = t & 31;   // col lane:  cols j + 32c

    float acc[8][8];
    #pragma unroll
    for (int r = 0; r < 8; ++r)
        #pragma unroll
        for (int c = 0; c < 8; ++c)
            acc[r][c] = 0.f;

    // ---- GEMM: H = X * W1  (M=64, N=256, K=256), K-tiled W1 staging ----
    for (int kt = 0; kt < FF / KT; ++kt) {
        __syncthreads();   // prev compute done (and Xs staged, on iter 0)
        {
            const float4* src = (const float4*)(W1 + kt * KT * FF);
            float4* dst = (float4*)smem2;
            #pragma unroll
            for (int q = 0; q < 4; ++q)
                dst[t + 256 * q] = src[t + 256 * q];
        }
        __syncthreads();
        #pragma unroll
        for (int ft = 0; ft < KT; ++ft) {
            const int f = kt * KT + ft;
            float xv[8], wv[8];
            #pragma unroll
            for (int r = 0; r < 8; ++r) xv[r] = Xs[(8 * i + r) * FF + f];
            #pragma unroll
            for (int c = 0; c < 8; ++c) wv[c] = smem2[ft * FF + j + 32 * c];
            #pragma unroll
            for (int r = 0; r < 8; ++r)
                #pragma unroll
                for (int c = 0; c < 8; ++c)
                    acc[r][c] = fmaf(xv[r], wv[c], acc[r][c]);
        }
    }
    __syncthreads();   // smem2 free for reuse

    // ---- epilogue layer 1+2: h = relu(acc+b1); partial = h . W2 ----
    float* SP   = smem2;             // [64][33] padded partials
    float* wbuf = smem2 + 64 * 33;   // [64] softmax weights

    float b1v[8], w2v[8];
    #pragma unroll
    for (int c = 0; c < 8; ++c) {
        b1v[c] = b1[j + 32 * c];
        w2v[c] = W2[j + 32 * c];
    }
    #pragma unroll
    for (int r = 0; r < 8; ++r) {
        float p = 0.f;
        #pragma unroll
        for (int c = 0; c < 8; ++c) {
            float h = fmaxf(acc[r][c] + b1v[c], 0.f);
            p = fmaf(h, w2v[c], p);
        }
        SP[(8 * i + r) * 33 + j] = p;
    }
    __syncthreads();

    // ---- scores + inverse-distance softmax over L (wave 0 only) ----
    if (t < LL) {
        const int l = t;
        float sum = 0.f;
        #pragma unroll
        for (int jj = 0; jj < 32; ++jj) sum += SP[l * 33 + jj];
        float score = fmaxf(sum + b2[0], 0.f);
        float dx = src_locs[(b * LL + l) * 2 + 0] - tar_locs[b * 2 + 0];
        float dy = src_locs[(b * LL + l) * 2 + 1] - tar_locs[b * 2 + 1];
        float inv = 1.0f / sqrtf(dx * dx + dy * dy);
        float logit = score * inv;
        float m = logit;
        #pragma unroll
        for (int o = 32; o > 0; o >>= 1) m = fmaxf(m, __shfl_xor(m, o));
        float e = __expf(logit - m);
        float se = e;
        #pragma unroll
        for (int o = 32; o > 0; o >>= 1) se += __shfl_xor(se, o);
        wbuf[l] = e / se;
    }
    __syncthreads();

    // ---- weighted sum over stations: out[bs][g] = sum_l Xs[l][g]*w[l] ----
    {
        const int g = t;
        float o = 0.f;
        #pragma unroll
        for (int l = 0; l < LL; ++l)
            o = fmaf(Xs[l * FF + g], wbuf[l], o);
        out[bs * FF + g] = o;
    }
}

extern "C" void kernel_launch(void* const* d_in, const int* in_sizes, int n_in,
                              void* d_out, int out_size, void* d_ws, size_t ws_size,
                              hipStream_t stream) {
    const float* features = (const float*)d_in[0];
    const float* src_locs = (const float*)d_in[1];
    const float* tar_locs = (const float*)d_in[2];
    const float* W1       = (const float*)d_in[3];
    const float* b1       = (const float*)d_in[4];
    const float* W2       = (const float*)d_in[5];
    const float* b2       = (const float*)d_in[6];
    float* out = (float*)d_out;

    ida_kernel<<<dim3(BB * SS), dim3(256), 0, stream>>>(
        features, src_locs, tar_locs, W1, b1, W2, b2, out);
}

// Round 2
// 185.102 us; speedup vs baseline: 2.3417x; 2.3417x over previous
//
#include <hip/hip_runtime.h>
#include <hip/hip_fp16.h>
#include <math.h>

typedef _Float16 half8 __attribute__((ext_vector_type(8)));
typedef float floatx4 __attribute__((ext_vector_type(4)));

#define BB 32
#define SS 48
#define LL 64
#define FF 256

// ---- prep: swizzle W1 (256x256 fp32) into fp16 hi/lo MFMA-B fragment order ----
// layout: flat = ((kt*16 + nt)*64 + lane)*8 + j
//   element = W1[kt*32 + (lane>>4)*8 + j][nt*16 + (lane&15)]
__global__ __launch_bounds__(256) void prep_w(const float* __restrict__ W1,
                                              _Float16* __restrict__ whi,
                                              _Float16* __restrict__ wlo) {
    int idx = blockIdx.x * 256 + threadIdx.x;
    int j    = idx & 7;
    int lane = (idx >> 3) & 63;
    int nt   = (idx >> 9) & 15;
    int kt   = idx >> 13;
    int k = kt * 32 + ((lane >> 4) & 3) * 8 + j;
    int n = nt * 16 + (lane & 15);
    float x = W1[k * FF + n];
    _Float16 hi = (_Float16)x;
    _Float16 lo = (_Float16)(x - (float)hi);
    whi[idx] = hi;
    wlo[idx] = lo;
}

// ---- main fused kernel: one block per (b,s) ----
__global__ __launch_bounds__(256, 2) void ida_mfma(
    const float* __restrict__ features,
    const float* __restrict__ src_locs,
    const float* __restrict__ tar_locs,
    const _Float16* __restrict__ whi,
    const _Float16* __restrict__ wlo,
    const float* __restrict__ b1,
    const float* __restrict__ W2,
    const float* __restrict__ b2,
    float* __restrict__ out)
{
    // A-fragment LDS, staged one K-half (4 kt of 32) at a time: 16 KiB + 16 KiB
    __shared__ _Float16 Ahi[8192];
    __shared__ _Float16 Alo[8192];
    __shared__ float SP[LL * 4];   // per-wave layer-2 partials [row][wave]
    __shared__ float wbuf[LL];     // softmax weights

    const int t    = threadIdx.x;
    const int w    = t >> 6;       // wave id 0..3
    const int lane = t & 63;
    const int quad = lane >> 4;
    const int l16  = lane & 15;
    const int bs   = blockIdx.x;
    const int b    = bs / SS;

    const float* Xg = features + (size_t)bs * (LL * FF);

    floatx4 acc[4][4] = {};        // [mt][nt], nt local to wave (global nt = 4w+nt)

    for (int half = 0; half < 2; ++half) {
        __syncthreads();           // previous half's A reads complete
        // stage+convert: wave w stages rows 16w..16w+15 into frag order
        #pragma unroll
        for (int ktl = 0; ktl < 4; ++ktl) {
            int kt  = half * 4 + ktl;
            int row = w * 16 + l16;
            int col = kt * 32 + quad * 8;
            const float4* p = (const float4*)(Xg + row * FF + col);
            float4 x0 = p[0], x1 = p[1];
            float xs[8] = {x0.x, x0.y, x0.z, x0.w, x1.x, x1.y, x1.z, x1.w};
            half8 hi, lo;
            #pragma unroll
            for (int j = 0; j < 8; ++j) {
                _Float16 h = (_Float16)xs[j];
                hi[j] = h;
                lo[j] = (_Float16)(xs[j] - (float)h);
            }
            *((half8*)&Ahi[((w * 4 + ktl) * 64 + lane) * 8]) = hi;
            *((half8*)&Alo[((w * 4 + ktl) * 64 + lane) * 8]) = lo;
        }
        __syncthreads();

        #pragma unroll
        for (int ktl = 0; ktl < 4; ++ktl) {
            int kt = half * 4 + ktl;
            half8 bhi[4], blo[4];
            #pragma unroll
            for (int nt = 0; nt < 4; ++nt) {
                int ntg = w * 4 + nt;
                size_t off = ((size_t)(kt * 16 + ntg) * 64 + lane) * 8;
                bhi[nt] = *((const half8*)(whi + off));
                blo[nt] = *((const half8*)(wlo + off));
            }
            #pragma unroll
            for (int mt = 0; mt < 4; ++mt) {
                half8 ahi = *((half8*)&Ahi[((mt * 4 + ktl) * 64 + lane) * 8]);
                half8 alo = *((half8*)&Alo[((mt * 4 + ktl) * 64 + lane) * 8]);
                #pragma unroll
                for (int nt = 0; nt < 4; ++nt) {
                    acc[mt][nt] = __builtin_amdgcn_mfma_f32_16x16x32_f16(ahi, bhi[nt], acc[mt][nt], 0, 0, 0);
                    acc[mt][nt] = __builtin_amdgcn_mfma_f32_16x16x32_f16(ahi, blo[nt], acc[mt][nt], 0, 0, 0);
                    acc[mt][nt] = __builtin_amdgcn_mfma_f32_16x16x32_f16(alo, bhi[nt], acc[mt][nt], 0, 0, 0);
                }
            }
        }
    }

    // ---- layer-2: partial[row] = sum_n relu(H + b1) * W2, per wave over its 64 cols ----
    float b1v[4], w2v[4];
    #pragma unroll
    for (int nt = 0; nt < 4; ++nt) {
        int n = (w * 4 + nt) * 16 + l16;
        b1v[nt] = b1[n];
        w2v[nt] = W2[n];
    }
    #pragma unroll
    for (int mt = 0; mt < 4; ++mt) {
        #pragma unroll
        for (int r = 0; r < 4; ++r) {
            float p = 0.f;
            #pragma unroll
            for (int nt = 0; nt < 4; ++nt) {
                float h = fmaxf(acc[mt][nt][r] + b1v[nt], 0.f);
                p = fmaf(h, w2v[nt], p);
            }
            // reduce across the 16 lanes (l16) sharing this row
            p += __shfl_xor(p, 1);
            p += __shfl_xor(p, 2);
            p += __shfl_xor(p, 4);
            p += __shfl_xor(p, 8);
            if (l16 == 0) SP[(mt * 16 + quad * 4 + r) * 4 + w] = p;
        }
    }
    __syncthreads();

    // ---- inverse-distance softmax over L=64 (wave 0) ----
    if (t < LL) {
        float s = SP[4 * t] + SP[4 * t + 1] + SP[4 * t + 2] + SP[4 * t + 3] + b2[0];
        float score = fmaxf(s, 0.f);
        float dx = src_locs[(b * LL + t) * 2 + 0] - tar_locs[b * 2 + 0];
        float dy = src_locs[(b * LL + t) * 2 + 1] - tar_locs[b * 2 + 1];
        float inv = 1.0f / sqrtf(dx * dx + dy * dy);
        float logit = score * inv;
        float m = logit;
        #pragma unroll
        for (int o = 32; o > 0; o >>= 1) m = fmaxf(m, __shfl_xor(m, o));
        float e = __expf(logit - m);
        float se = e;
        #pragma unroll
        for (int o = 32; o > 0; o >>= 1) se += __shfl_xor(se, o);
        wbuf[t] = e / se;
    }
    __syncthreads();

    // ---- weighted sum over stations: out[bs][g] = sum_l X[l][g] * wbuf[l] ----
    {
        float o = 0.f;
        #pragma unroll 8
        for (int l = 0; l < LL; ++l)
            o = fmaf(Xg[l * FF + t], wbuf[l], o);
        out[bs * FF + t] = o;
    }
}

extern "C" void kernel_launch(void* const* d_in, const int* in_sizes, int n_in,
                              void* d_out, int out_size, void* d_ws, size_t ws_size,
                              hipStream_t stream) {
    const float* features = (const float*)d_in[0];
    const float* src_locs = (const float*)d_in[1];
    const float* tar_locs = (const float*)d_in[2];
    const float* W1       = (const float*)d_in[3];
    const float* b1       = (const float*)d_in[4];
    const float* W2       = (const float*)d_in[5];
    const float* b2       = (const float*)d_in[6];
    float* out = (float*)d_out;

    _Float16* whi = (_Float16*)d_ws;               // 65536 fp16 = 128 KiB
    _Float16* wlo = whi + FF * FF;                 // 128 KiB more

    prep_w<<<dim3(FF * FF / 256), dim3(256), 0, stream>>>(W1, whi, wlo);
    ida_mfma<<<dim3(BB * SS), dim3(256), 0, stream>>>(
        features, src_locs, tar_locs, whi, wlo, b1, W2, b2, out);
}